// Round 17
// baseline (428.548 us; speedup 1.0000x reference)
//
#include <hip/hip_runtime.h>
#include <hip/hip_fp16.h>
#include <math.h>

#define HH    1024
#define WWID  1024
#define WR    513
#define NIMG  96
#define NGRP  65
#define KSEG  17
#define FEAT  256
#define FIN   144

#if defined(__has_builtin)
#if __has_builtin(__builtin_amdgcn_permlane32_swap)
#define PERM32 1
#endif
#endif
#ifndef PERM32
#define PERM32 0
#endif

__device__ __forceinline__ float2 cmul(float2 a, float2 b) {
    return make_float2(a.x * b.x - a.y * b.y, a.x * b.y + a.y * b.x);
}

// exact reference binning (16 compares + sqrt) — used by k_counts
__device__ __forceinline__ int radial_bin(int hf, int k) {
    const float maxr = 0.707106781186547524f;
    float v = (float)(hf < 512 ? hf : hf - 1024) * (1.0f / 1024.0f);
    float u = (float)k * (1.0f / 1024.0f);
    float rad = sqrtf(u * u + v * v);
    int bin = 0;
#pragma unroll
    for (int l = 1; l <= 16; ++l) {
        float lower = (maxr * (float)l) * 0.0625f;
        bin += (rad >= lower) ? 1 : 0;
    }
    return bin;
}

// fast bin with exact boundary adjust (validated r6-r16)
__device__ __forceinline__ int fast_bin(float rad) {
    int c = (int)(rad * 22.62741699796952f);
    if (c > 16) c = 16;
    if (c < 16 && rad >= (0.707106781186547524f * (float)(c + 1)) * 0.0625f) c++;
    else if (rad < (0.707106781186547524f * (float)c) * 0.0625f) c--;
    return c;
}

__device__ constexpr int BR4[16] = {0,8,4,12,2,10,6,14,1,9,5,13,3,11,7,15};

// ---- cross-lane exchange: DPP where exact, ds ops otherwise (verified r12) ----------
template<int HALF>
__device__ __forceinline__ float sxl(float v, int addr32) {
    int vi = __float_as_int(v);
    if constexpr (HALF == 32)
        return __int_as_float(__builtin_amdgcn_ds_bpermute(addr32, vi));
    else if constexpr (HALF == 8)
        return __int_as_float(__builtin_amdgcn_update_dpp(vi, vi, 0x128, 0xF, 0xF, true));
    else if constexpr (HALF == 2)
        return __int_as_float(__builtin_amdgcn_update_dpp(vi, vi, 0x4E, 0xF, 0xF, true));
    else if constexpr (HALF == 1)
        return __int_as_float(__builtin_amdgcn_update_dpp(vi, vi, 0xB1, 0xF, 0xF, true));
    else
        return __int_as_float(__builtin_amdgcn_ds_swizzle(vi, (HALF << 10) | 0x1F));
}

template<int HALF>
__device__ __forceinline__ void fftC_stage(float2 a[16], int l, float2 u, int addr32) {
    const bool up = (l & HALF) != 0;
    const float sgn = up ? -1.0f : 1.0f;
    const float twx = up ? -u.x : 1.0f;   // down lanes: identity twiddle
    const float twy = up ? -u.y : 0.0f;
#pragma unroll
    for (int r = 0; r < 16; ++r) {
        float ox = sxl<HALF>(a[r].x, addr32);
        float oy = sxl<HALF>(a[r].y, addr32);
        float sx = fmaf(sgn, a[r].x, ox);   // down: a+o, up: o-a
        float sy = fmaf(sgn, a[r].y, oy);
        a[r].x = fmaf(sx, twx, -(sy * twy));
        a[r].y = fmaf(sx, twy, sy * twx);
    }
}

// stages 16..1 (shared). u must be W_32^l on entry.
__device__ __forceinline__ void wave_fft_C_tail(float2 a[16], int l, float2 u) {
    fftC_stage<16>(a, l, u, 0); u = cmul(u, u);
    fftC_stage<8>(a, l, u, 0);  u = cmul(u, u);
    fftC_stage<4>(a, l, u, 0);  u = cmul(u, u);
    fftC_stage<2>(a, l, u, 0);  u = cmul(u, u);
    fftC_stage<1>(a, l, u, 0);
}

// standard 64-pt DIF across lanes (rowfft). natural in -> bitrev out.
__device__ __forceinline__ void wave_fft_C(float2 a[16], int l, float2 u) {
    const int addr32 = ((l ^ 32) << 2);
    fftC_stage<32>(a, l, u, addr32);
    u = cmul(u, u);
    wave_fft_C_tail(a, l, u);
}

#if PERM32
// 64-pt DIF with stage-32 via permlane32_swap mixing (verified r11/r12).
__device__ __forceinline__ void wave_fft_C_mix(float2 a[16], int l, float2 u) {
    const bool lo = (l < 32);
    const float2 t = lo ? u : make_float2(-u.x, -u.y);
#pragma unroll
    for (int r = 0; r < 8; ++r) {
        unsigned ax = __float_as_uint(a[r].x), bx = __float_as_uint(a[r + 8].x);
        auto px = __builtin_amdgcn_permlane32_swap(ax, bx, false, false);
        unsigned ay = __float_as_uint(a[r].y), by = __float_as_uint(a[r + 8].y);
        auto py = __builtin_amdgcn_permlane32_swap(ay, by, false, false);
        float l0x = __uint_as_float(px[0]), h0x = __uint_as_float(px[1]);
        float l0y = __uint_as_float(py[0]), h0y = __uint_as_float(py[1]);
        a[r]     = make_float2(l0x + h0x, l0y + h0y);          // S_r
        a[r + 8] = cmul(make_float2(l0x - h0x, l0y - h0y), t); // T_r
    }
    u = cmul(u, u);
    wave_fft_C_tail(a, l, u);
}
#endif

// 16-pt DIT over registers: input reg r = element BR4[r] (bitrev order), natural out.
__device__ __forceinline__ void fft16_regs(float2 a[16]) {
    constexpr float TW16C[8] = {1.f, 0.9238795325112867f, 0.7071067811865476f,
                                0.3826834323650898f, 0.f, -0.3826834323650898f,
                                -0.7071067811865476f, -0.9238795325112867f};
    constexpr float TW16S[8] = {0.f, -0.3826834323650898f, -0.7071067811865476f,
                                -0.9238795325112867f, -1.f, -0.9238795325112867f,
                                -0.7071067811865476f, -0.3826834323650898f};
#pragma unroll
    for (int m = 2; m <= 16; m <<= 1) {
        const int half = m >> 1;
        const int tstep = 16 / m;
#pragma unroll
        for (int bse = 0; bse < 16; bse += m) {
#pragma unroll
            for (int jj = 0; jj < 8; ++jj) {
                if (jj < half) {
                    float2 w = make_float2(TW16C[jj * tstep], TW16S[jj * tstep]);
                    float2 tv = cmul(a[bse + half + jj], w);
                    float2 u0 = a[bse + jj];
                    a[bse + jj]        = make_float2(u0.x + tv.x, u0.y + tv.y);
                    a[bse + half + jj] = make_float2(u0.x - tv.x, u0.y - tv.y);
                }
            }
        }
    }
}

// twiddle a[r] *= wb^{e_r}; wb from __cosf/__sinf (|ang|<=0.39 rad), two-level chain.
template<bool PERM>  // e_r = PERM ? BR4[r] : r
__device__ __forceinline__ void twiddle_regs(float2 a[16], float ang, float2* w16out) {
    float2 w1 = make_float2(__cosf(ang), __sinf(ang));
    float2 w2 = cmul(w1, w1);
    float2 w3 = cmul(w2, w1);
    float2 w4 = cmul(w2, w2);
    float2 w8 = cmul(w4, w4);
    float2 w12 = cmul(w8, w4);
#pragma unroll
    for (int r = 1; r < 16; ++r) {
        const int e = PERM ? BR4[r] : r;
        float2 p = a[r];
        const int hi = e >> 2, lo = e & 3;
        if (hi == 1) p = cmul(p, w4);
        else if (hi == 2) p = cmul(p, w8);
        else if (hi == 3) p = cmul(p, w12);
        if (lo == 1) p = cmul(p, w1);
        else if (lo == 2) p = cmul(p, w2);
        else if (lo == 3) p = cmul(p, w3);
        a[r] = p;
    }
    if (w16out) *w16out = cmul(w8, w8);
}

// ---------------- Kernel 1: row FFTs — 512 threads, 8 pairs/block, 3 blocks/CU -------
// Pairing: Z_q = row q + i*row(q+512); this block's q = blk + 64w, w = wave 0..7.
// interm position p(q) = 8*(q&63) + (q>>6) = blk*8 + w  — IDENTICAL layout to r16.
__global__ __launch_bounds__(512) void k_rowfft(const float* __restrict__ x,
                                                __half2* __restrict__ interm,
                                                int img0) {
    __shared__ __half2 tile[1024][9];  // stride 9: gcd(9,32)=1 -> 2-way banks
    const int t = threadIdx.x;
    const int w = t >> 6;              // 0..7
    const int l = t & 63;
    const int blk = blockIdx.x;        // 0..63
    const int iy = blockIdx.y;
    const int img = img0 + iy;
    const int hA = blk + 64 * w;
    const int hB = hA + 512;

    const float4* r1 = (const float4*)(x + ((size_t)img * HH + hA) * WWID) + 4 * l;
    const float4* r2 = (const float4*)(x + ((size_t)img * HH + hB) * WWID) + 4 * l;

    // consume each staged float4 immediately -> low staging pressure
    float2 a[16];
#pragma unroll
    for (int c = 0; c < 4; ++c) {
        float4 v1 = r1[c];
        float4 v2 = r2[c];
        a[BR4[4 * c + 0]] = make_float2(v1.x, v2.x);
        a[BR4[4 * c + 1]] = make_float2(v1.y, v2.y);
        a[BR4[4 * c + 2]] = make_float2(v1.z, v2.z);
        a[BR4[4 * c + 3]] = make_float2(v1.w, v2.w);
    }

    float angL = (float)l * (-6.28318530717958647692f / 64.0f);
    wave_fft_C(a, l, make_float2(__cosf(angL), __sinf(angL)));

    const int b = (int)(__brev((unsigned)l) >> 26);
    float angB = (float)b * (-6.28318530717958647692f / 1024.0f);
    twiddle_regs<true>(a, angB, nullptr);
    fft16_regs(a);

#pragma unroll
    for (int r = 0; r < 16; ++r)
        tile[b + 64 * r][w] = __floats2half2_rn(a[r].x, a[r].y);
    __syncthreads();

    // write-out: 1024 rows x 2 uint4 = 2048 uint4; 4 iterations of 512 threads
    uint4* gout4 = (uint4*)(interm + (size_t)iy * 1024 * 512);
#pragma unroll
    for (int it = 0; it < 4; ++it) {
        int idx = t + it * 512;           // 0..2047
        int k = idx >> 1;                 // 0..1023
        int j = idx & 1;
        uint4 v;
        v.x = *(const unsigned*)&tile[k][4 * j + 0];
        v.y = *(const unsigned*)&tile[k][4 * j + 1];
        v.z = *(const unsigned*)&tile[k][4 * j + 2];
        v.w = *(const unsigned*)&tile[k][4 * j + 3];
        gout4[(size_t)k * 128 + blk * 2 + j] = v;
    }
}

// ------------- Kernel 2: column FFTs — loads hoisted above zero+barrier (r16) --------
__global__ __launch_bounds__(512) void k_colfft(const __half2* __restrict__ interm,
                                                float* __restrict__ partials,
                                                int img0) {
    __shared__ float wsum[8][KSEG][8][2];      // [wave][bin][slot][s1,s2]
    __shared__ unsigned wmax[8][KSEG][8];
    const int t = threadIdx.x;
    const int g = blockIdx.x;
    const int iy = blockIdx.y;
    const int img = img0 + iy;
    const int wv = t >> 6;
    const int l = t & 63;
    const int k = g * 8 + wv;
    const int slot = l & 7;

    // issue global loads FIRST: latency hides under the LDS zeroing + barrier
    uint4 q0, q1, q2, q3;
    if (k <= 512) {   // wave-uniform
        const int kn = (1024 - k) & 1023;
        const uint4* ps = (const uint4*)(interm + ((size_t)iy * 1024 + k) * 512 + l * 8);
        const uint4* pn = (const uint4*)(interm + ((size_t)iy * 1024 + kn) * 512 + l * 8);
        q0 = ps[0]; q1 = ps[1];
        q2 = pn[0]; q3 = pn[1];
    }

    for (int i = t; i < 8 * 136; i += 512) {
        int w = i / 136;
        int rem = i - w * 136;
        int bb = rem >> 3, sl = rem & 7;
        wsum[w][bb][sl][0] = 0.f;
        wsum[w][bb][sl][1] = 0.f;
        wmax[w][bb][sl] = 0u;
    }
    __syncthreads();

    if (k <= 512) {   // wave-uniform
        // unpack (0.5 factors folded into c1/c2, r12)
        float2 a[16];
        {
            union QU { uint4 q; __half2 h[4]; } us, un;
#pragma unroll
            for (int c = 0; c < 2; ++c) {
                us.q = c ? q1 : q0;
                un.q = c ? q3 : q2;
#pragma unroll
                for (int j = 0; j < 4; ++j) {
                    int m = 4 * c + j;
                    float2 zs = __half22float2(us.h[j]);
                    float2 zn = __half22float2(un.h[j]);
                    a[BR4[m]]     = make_float2(zs.x + zn.x, zs.y - zn.y);
                    a[BR4[m + 8]] = make_float2(zs.y + zn.y, zn.x - zs.x);
                }
            }
        }

        fft16_regs(a);
        float2 u16;
        float angB = (float)l * (-6.28318530717958647692f / 1024.0f);
        twiddle_regs<false>(a, angB, &u16);
#if PERM32
        wave_fft_C_mix(a, l, u16);
#else
        wave_fft_C(a, l, u16);
#endif

        // ---- stats: two 8-row runs per lane (span <= 24 rows -> at most 2 bins) ----
        const int b = (int)(__brev((unsigned)l) >> 26);
#if PERM32
        const int bX = b ^ 1;
        const bool lohalf = (l < 32);
        const int offS = lohalf ? 0 : 8;
        const int hS0 = 16 * (lohalf ? b : bX) + offS;   // rows for slots 0..7
        const int hT0 = 16 * (lohalf ? bX : b) + offS;   // rows for slots 8..15
        const int hmin = 16 * (b & ~1) + offS;
        const int hmax = 16 * (b | 1) + offS + 7;
#else
        const int hS0 = 16 * b;
        const int hT0 = 16 * b + 8;
        const int hmin = 16 * b;
        const int hmax = 16 * b + 15;
#endif
        const float uf = (float)k * (1.0f / 1024.0f);
        const float uu = uf * uf;
        const float vbS = (float)(hS0 < 512 ? hS0 : hS0 - 1024);
        const float vbT = (float)(hT0 < 512 ? hT0 : hT0 - 1024);
        float vmn = (float)(hmin < 512 ? hmin : hmin - 1024) * (1.0f / 1024.0f);
        float vmx = (float)(hmax < 512 ? hmax : hmax - 1024) * (1.0f / 1024.0f);
        int binF = fast_bin(sqrtf(fmaf(vmn, vmn, uu)));
        int binL = fast_bin(sqrtf(fmaf(vmx, vmx, uu)));
        const int bHi = (binF > binL) ? binF : binL;
        const float Lmid = (0.707106781186547524f * (float)bHi) * 0.0625f;
        const float Lmid2 = Lmid * Lmid;

        // totals + B-side; A-side derived (sA = sT - sB)
        float sT1 = 0.f, sT2 = 0.f, mA = 0.f;
        float sB1 = 0.f, sB2 = 0.f, mB = 0.f;
#pragma unroll
        for (int r = 0; r < 16; ++r) {
            float vf = (r < 8 ? (vbS + (float)r) : (vbT + (float)(r - 8)))
                       * (1.0f / 1024.0f);
            float s = fmaf(vf, vf, uu);                    // exact rad^2
            float2 z = a[r];
            float p2 = fmaf(z.x, z.x, z.y * z.y);
            float m = sqrtf(p2);
            bool c = (s >= Lmid2);                         // row in bin bHi
            sT1 += m;
            sT2 += p2;
            mA = fmaxf(mA, c ? m : 0.f);
            sB1 += c ? 0.f : m;
            sB2 += c ? 0.f : p2;
            mB = fmaxf(mB, c ? 0.f : m);
        }
        // values are 2x reference: c1 = 1/2048, c2 = 1/4194304 (exact pow2, r12)
        const float c1 = 1.0f / 2048.0f;
        const float c2 = 1.0f / 4194304.0f;
        float sA1 = sT1 - sB1;
        float sA2 = sT2 - sB2;

        atomicAdd(&wsum[wv][bHi][slot][0], sA1 * c1);
        atomicAdd(&wsum[wv][bHi][slot][1], sA2 * c2);
        atomicMax(&wmax[wv][bHi][slot], __float_as_uint(mA * c1));
        if (bHi > 0) {
            atomicAdd(&wsum[wv][bHi - 1][slot][0], sB1 * c1);
            atomicAdd(&wsum[wv][bHi - 1][slot][1], sB2 * c2);
            atomicMax(&wmax[wv][bHi - 1][slot], __float_as_uint(mB * c1));
        }
    }
    __syncthreads();

    if (t < KSEG) {
        float aS = 0.f, bS = 0.f, cM = 0.f;
#pragma unroll
        for (int w = 0; w < 8; ++w)
#pragma unroll
            for (int sl = 0; sl < 8; ++sl) {
                aS += wsum[w][t][sl][0];
                bS += wsum[w][t][sl][1];
                cM = fmaxf(cM, __uint_as_float(wmax[w][t][sl]));
            }
        float* dstp = partials + ((size_t)img * NGRP + g) * (KSEG * 3) + t * 3;
        dstp[0] = aS; dstp[1] = bS; dstp[2] = cM;
    }
}

// ---------------- counts (exact reference binning, no int division) ------------------
__global__ __launch_bounds__(256) void k_counts(unsigned* __restrict__ counts) {
    int cnt[KSEG];
#pragma unroll
    for (int l = 0; l < KSEG; ++l) cnt[l] = 0;
    const int tid = blockIdx.x * 256 + threadIdx.x;
    const int stride = gridDim.x * 256;
    for (int i = tid; i < 1024 * 512; i += stride) {
        int h = i >> 9;
        int k = i & 511;
        int bin = radial_bin(h, k);
#pragma unroll
        for (int l = 0; l < KSEG; ++l) cnt[l] += (bin == l) ? 1 : 0;
    }
    for (int j = tid; j < 1024; j += stride) {   // k = 512 column
        int bin = radial_bin(j, 512);
#pragma unroll
        for (int l = 0; l < KSEG; ++l) cnt[l] += (bin == l) ? 1 : 0;
    }
    const int lane = threadIdx.x & 63;
#pragma unroll
    for (int l = 0; l < KSEG; ++l) {
        int c = cnt[l];
        for (int off = 32; off > 0; off >>= 1) c += __shfl_xor(c, off);
        if (lane == 0 && c > 0) atomicAdd(&counts[l], (unsigned)c);
    }
}

// ---------------- Kernel 3: finalize stats + MLP + LayerNorm -------------------------
__global__ __launch_bounds__(256) void k_mlp(const float* __restrict__ partials,
                                             const unsigned* __restrict__ counts,
                                             const float* __restrict__ W1,
                                             const float* __restrict__ b1,
                                             const float* __restrict__ W2,
                                             const float* __restrict__ b2,
                                             const float* __restrict__ gamma,
                                             const float* __restrict__ beta,
                                             float* __restrict__ out) {
    __shared__ float feat[FIN];
    __shared__ float h1s[FEAT];
    __shared__ float red[FEAT];
    const int b = blockIdx.x;
    const int t = threadIdx.x;
    if (t < 48) {
        int c = t / 16;
        int bin = t % 16;
        const float* p = partials + ((size_t)(b * 3 + c) * NGRP) * (KSEG * 3) + bin * 3;
        float s1 = 0.f, s2 = 0.f, mxv = 0.f;
        for (int gg = 0; gg < NGRP; ++gg) {
            s1 += p[gg * (KSEG * 3) + 0];
            s2 += p[gg * (KSEG * 3) + 1];
            mxv = fmaxf(mxv, p[gg * (KSEG * 3) + 2]);
        }
        float cntf = (float)counts[bin];
        float denom = cntf + 1e-8f;
        float mean = s1 / denom;
        float var = (s2 - 2.0f * mean * s1 + cntf * mean * mean) / denom;
        var = fmaxf(var, 0.0f);
        float sd = sqrtf(var);
        mxv = fmaxf(mxv, 0.0f);
        feat[bin * 9 + 0 + c] = mean;
        feat[bin * 9 + 3 + c] = mxv;
        feat[bin * 9 + 6 + c] = sd;
    }
    __syncthreads();

    float acc = b1[t];
    for (int i = 0; i < FIN; ++i) acc += feat[i] * W1[i * FEAT + t];
    acc = (acc >= 0.0f) ? acc : 0.2f * acc;
    h1s[t] = acc;
    __syncthreads();

    float acc2 = b2[t];
    for (int i = 0; i < FEAT; ++i) acc2 += h1s[i] * W2[i * FEAT + t];

    red[t] = acc2;
    __syncthreads();
    for (int off = 128; off > 0; off >>= 1) {
        if (t < off) red[t] += red[t + off];
        __syncthreads();
    }
    float mu = red[0] * (1.0f / 256.0f);
    __syncthreads();
    float dvt = acc2 - mu;
    red[t] = dvt * dvt;
    __syncthreads();
    for (int off = 128; off > 0; off >>= 1) {
        if (t < off) red[t] += red[t + off];
        __syncthreads();
    }
    float va = red[0] * (1.0f / 256.0f);
    out[(size_t)b * FEAT + t] = dvt / sqrtf(va + 1e-5f) * gamma[t] + beta[t];
}

// --------------------------------------------------------------------------------------
extern "C" void kernel_launch(void* const* d_in, const int* in_sizes, int n_in,
                              void* d_out, int out_size, void* d_ws, size_t ws_size,
                              hipStream_t stream) {
    const float* x     = (const float*)d_in[0];
    const float* W1    = (const float*)d_in[1];
    const float* b1    = (const float*)d_in[2];
    const float* W2    = (const float*)d_in[3];
    const float* b2    = (const float*)d_in[4];
    const float* gamma = (const float*)d_in[5];
    const float* beta  = (const float*)d_in[6];
    float* out = (float*)d_out;

    char* ws = (char*)d_ws;
    unsigned* counts = (unsigned*)ws;
    float* partials = (float*)(ws + 256);
    const size_t partialsBytes = (size_t)NIMG * NGRP * KSEG * 3 * sizeof(float);
    const size_t intermOff = (256 + partialsBytes + 255) & ~(size_t)255;
    __half2* interm = (__half2*)(ws + intermOff);
    const size_t perImg = (size_t)1024 * 512 * sizeof(__half2);

    long long avail = (long long)ws_size - (long long)intermOff;
    int chunk = (avail > 0) ? (int)(avail / (long long)perImg) : 0;
    if (chunk > NIMG) chunk = NIMG;
    if (chunk < 1) chunk = 1;

    hipMemsetAsync(counts, 0, KSEG * sizeof(unsigned), stream);
    k_counts<<<dim3(128), dim3(256), 0, stream>>>(counts);

    for (int img0 = 0; img0 < NIMG; img0 += chunk) {
        int n = NIMG - img0;
        if (n > chunk) n = chunk;
        k_rowfft<<<dim3(64, n), dim3(512), 0, stream>>>(x, interm, img0);
        k_colfft<<<dim3(NGRP, n), dim3(512), 0, stream>>>(interm, partials, img0);
    }

    k_mlp<<<dim3(32), dim3(256), 0, stream>>>(partials, counts, W1, b1, W2, b2,
                                              gamma, beta, out);
}

// Round 18
// 410.948 us; speedup vs baseline: 1.0428x; 1.0428x over previous
//
#include <hip/hip_runtime.h>
#include <hip/hip_fp16.h>
#include <math.h>

#define HH    1024
#define WWID  1024
#define WR    513
#define NIMG  96
#define NGRP  65
#define KSEG  17
#define FEAT  256
#define FIN   144
#define CHUNK_IMGS 32   // 32 x 4.19 MB = 134 MB interm slab -> L3-resident for colfft

#if defined(__has_builtin)
#if __has_builtin(__builtin_amdgcn_permlane32_swap)
#define PERM32 1
#endif
#endif
#ifndef PERM32
#define PERM32 0
#endif

__device__ __forceinline__ float2 cmul(float2 a, float2 b) {
    return make_float2(a.x * b.x - a.y * b.y, a.x * b.y + a.y * b.x);
}

// exact reference binning (16 compares + sqrt) — used by k_counts
__device__ __forceinline__ int radial_bin(int hf, int k) {
    const float maxr = 0.707106781186547524f;
    float v = (float)(hf < 512 ? hf : hf - 1024) * (1.0f / 1024.0f);
    float u = (float)k * (1.0f / 1024.0f);
    float rad = sqrtf(u * u + v * v);
    int bin = 0;
#pragma unroll
    for (int l = 1; l <= 16; ++l) {
        float lower = (maxr * (float)l) * 0.0625f;
        bin += (rad >= lower) ? 1 : 0;
    }
    return bin;
}

// fast bin with exact boundary adjust (validated r6-r16)
__device__ __forceinline__ int fast_bin(float rad) {
    int c = (int)(rad * 22.62741699796952f);
    if (c > 16) c = 16;
    if (c < 16 && rad >= (0.707106781186547524f * (float)(c + 1)) * 0.0625f) c++;
    else if (rad < (0.707106781186547524f * (float)c) * 0.0625f) c--;
    return c;
}

__device__ constexpr int BR4[16] = {0,8,4,12,2,10,6,14,1,9,5,13,3,11,7,15};

// ---- cross-lane exchange: DPP where exact, ds ops otherwise (verified r12) ----------
template<int HALF>
__device__ __forceinline__ float sxl(float v, int addr32) {
    int vi = __float_as_int(v);
    if constexpr (HALF == 32)
        return __int_as_float(__builtin_amdgcn_ds_bpermute(addr32, vi));
    else if constexpr (HALF == 8)
        return __int_as_float(__builtin_amdgcn_update_dpp(vi, vi, 0x128, 0xF, 0xF, true));
    else if constexpr (HALF == 2)
        return __int_as_float(__builtin_amdgcn_update_dpp(vi, vi, 0x4E, 0xF, 0xF, true));
    else if constexpr (HALF == 1)
        return __int_as_float(__builtin_amdgcn_update_dpp(vi, vi, 0xB1, 0xF, 0xF, true));
    else
        return __int_as_float(__builtin_amdgcn_ds_swizzle(vi, (HALF << 10) | 0x1F));
}

template<int HALF>
__device__ __forceinline__ void fftC_stage(float2 a[16], int l, float2 u, int addr32) {
    const bool up = (l & HALF) != 0;
    const float sgn = up ? -1.0f : 1.0f;
    const float twx = up ? -u.x : 1.0f;   // down lanes: identity twiddle
    const float twy = up ? -u.y : 0.0f;
#pragma unroll
    for (int r = 0; r < 16; ++r) {
        float ox = sxl<HALF>(a[r].x, addr32);
        float oy = sxl<HALF>(a[r].y, addr32);
        float sx = fmaf(sgn, a[r].x, ox);   // down: a+o, up: o-a
        float sy = fmaf(sgn, a[r].y, oy);
        a[r].x = fmaf(sx, twx, -(sy * twy));
        a[r].y = fmaf(sx, twy, sy * twx);
    }
}

// stages 16..1 (shared). u must be W_32^l on entry.
__device__ __forceinline__ void wave_fft_C_tail(float2 a[16], int l, float2 u) {
    fftC_stage<16>(a, l, u, 0); u = cmul(u, u);
    fftC_stage<8>(a, l, u, 0);  u = cmul(u, u);
    fftC_stage<4>(a, l, u, 0);  u = cmul(u, u);
    fftC_stage<2>(a, l, u, 0);  u = cmul(u, u);
    fftC_stage<1>(a, l, u, 0);
}

// standard 64-pt DIF across lanes (rowfft). natural in -> bitrev out.
__device__ __forceinline__ void wave_fft_C(float2 a[16], int l, float2 u) {
    const int addr32 = ((l ^ 32) << 2);
    fftC_stage<32>(a, l, u, addr32);
    u = cmul(u, u);
    wave_fft_C_tail(a, l, u);
}

#if PERM32
// 64-pt DIF with stage-32 via permlane32_swap mixing (verified r11/r12).
__device__ __forceinline__ void wave_fft_C_mix(float2 a[16], int l, float2 u) {
    const bool lo = (l < 32);
    const float2 t = lo ? u : make_float2(-u.x, -u.y);
#pragma unroll
    for (int r = 0; r < 8; ++r) {
        unsigned ax = __float_as_uint(a[r].x), bx = __float_as_uint(a[r + 8].x);
        auto px = __builtin_amdgcn_permlane32_swap(ax, bx, false, false);
        unsigned ay = __float_as_uint(a[r].y), by = __float_as_uint(a[r + 8].y);
        auto py = __builtin_amdgcn_permlane32_swap(ay, by, false, false);
        float l0x = __uint_as_float(px[0]), h0x = __uint_as_float(px[1]);
        float l0y = __uint_as_float(py[0]), h0y = __uint_as_float(py[1]);
        a[r]     = make_float2(l0x + h0x, l0y + h0y);          // S_r
        a[r + 8] = cmul(make_float2(l0x - h0x, l0y - h0y), t); // T_r
    }
    u = cmul(u, u);
    wave_fft_C_tail(a, l, u);
}
#endif

// 16-pt DIT over registers: input reg r = element BR4[r] (bitrev order), natural out.
__device__ __forceinline__ void fft16_regs(float2 a[16]) {
    constexpr float TW16C[8] = {1.f, 0.9238795325112867f, 0.7071067811865476f,
                                0.3826834323650898f, 0.f, -0.3826834323650898f,
                                -0.7071067811865476f, -0.9238795325112867f};
    constexpr float TW16S[8] = {0.f, -0.3826834323650898f, -0.7071067811865476f,
                                -0.9238795325112867f, -1.f, -0.9238795325112867f,
                                -0.7071067811865476f, -0.3826834323650898f};
#pragma unroll
    for (int m = 2; m <= 16; m <<= 1) {
        const int half = m >> 1;
        const int tstep = 16 / m;
#pragma unroll
        for (int bse = 0; bse < 16; bse += m) {
#pragma unroll
            for (int jj = 0; jj < 8; ++jj) {
                if (jj < half) {
                    float2 w = make_float2(TW16C[jj * tstep], TW16S[jj * tstep]);
                    float2 tv = cmul(a[bse + half + jj], w);
                    float2 u0 = a[bse + jj];
                    a[bse + jj]        = make_float2(u0.x + tv.x, u0.y + tv.y);
                    a[bse + half + jj] = make_float2(u0.x - tv.x, u0.y - tv.y);
                }
            }
        }
    }
}

// twiddle a[r] *= wb^{e_r}; wb from __cosf/__sinf (|ang|<=0.39 rad), two-level chain.
template<bool PERM>  // e_r = PERM ? BR4[r] : r
__device__ __forceinline__ void twiddle_regs(float2 a[16], float ang, float2* w16out) {
    float2 w1 = make_float2(__cosf(ang), __sinf(ang));
    float2 w2 = cmul(w1, w1);
    float2 w3 = cmul(w2, w1);
    float2 w4 = cmul(w2, w2);
    float2 w8 = cmul(w4, w4);
    float2 w12 = cmul(w8, w4);
#pragma unroll
    for (int r = 1; r < 16; ++r) {
        const int e = PERM ? BR4[r] : r;
        float2 p = a[r];
        const int hi = e >> 2, lo = e & 3;
        if (hi == 1) p = cmul(p, w4);
        else if (hi == 2) p = cmul(p, w8);
        else if (hi == 3) p = cmul(p, w12);
        if (lo == 1) p = cmul(p, w1);
        else if (lo == 2) p = cmul(p, w2);
        else if (lo == 3) p = cmul(p, w3);
        a[r] = p;
    }
    if (w16out) *w16out = cmul(w8, w8);
}

// ---------------- Kernel 1: row FFTs (r16 config: 1024 thr, 32 blocks) ---------------
__global__ __launch_bounds__(1024) void k_rowfft(const float* __restrict__ x,
                                                 __half2* __restrict__ interm,
                                                 int img0) {
    __shared__ __half2 tile[1024][17];
    const int t = threadIdx.x;
    const int w = t >> 6;
    const int l = t & 63;
    const int blk = blockIdx.x;           // 0..31
    const int iy = blockIdx.y;
    const int img = img0 + iy;
    const int hA = ((w & 7) << 6) + 2 * blk + (w >> 3);
    const int hB = hA + 512;

    const float4* r1 = (const float4*)(x + ((size_t)img * HH + hA) * WWID) + 4 * l;
    const float4* r2 = (const float4*)(x + ((size_t)img * HH + hB) * WWID) + 4 * l;

    // consume each staged float4 immediately -> low staging pressure (r13 keep)
    float2 a[16];
#pragma unroll
    for (int c = 0; c < 4; ++c) {
        float4 v1 = r1[c];
        float4 v2 = r2[c];
        a[BR4[4 * c + 0]] = make_float2(v1.x, v2.x);
        a[BR4[4 * c + 1]] = make_float2(v1.y, v2.y);
        a[BR4[4 * c + 2]] = make_float2(v1.z, v2.z);
        a[BR4[4 * c + 3]] = make_float2(v1.w, v2.w);
    }

    float angL = (float)l * (-6.28318530717958647692f / 64.0f);
    wave_fft_C(a, l, make_float2(__cosf(angL), __sinf(angL)));

    const int b = (int)(__brev((unsigned)l) >> 26);
    float angB = (float)b * (-6.28318530717958647692f / 1024.0f);
    twiddle_regs<true>(a, angB, nullptr);
    fft16_regs(a);

#pragma unroll
    for (int r = 0; r < 16; ++r)
        tile[b + 64 * r][w] = __floats2half2_rn(a[r].x, a[r].y);
    __syncthreads();

    // vectorized write-out: 1024 rows x 4 uint4 = 4096 uint4 -> FOUR iterations
    uint4* gout4 = (uint4*)(interm + (size_t)iy * 1024 * 512);
#pragma unroll
    for (int it = 0; it < 4; ++it) {
        int idx = t + it * 1024;          // 0..4095
        int k = idx >> 2;                 // 0..1023
        int j = idx & 3;
        uint4 v;
        v.x = *(const unsigned*)&tile[k][4 * j + 0];
        v.y = *(const unsigned*)&tile[k][4 * j + 1];
        v.z = *(const unsigned*)&tile[k][4 * j + 2];
        v.w = *(const unsigned*)&tile[k][4 * j + 3];
        gout4[(size_t)k * 128 + blk * 4 + j] = v;
    }
}

// ------------- Kernel 2: column FFTs — loads hoisted above zero+barrier (r16) --------
__global__ __launch_bounds__(512) void k_colfft(const __half2* __restrict__ interm,
                                                float* __restrict__ partials,
                                                int img0) {
    __shared__ float wsum[8][KSEG][8][2];      // [wave][bin][slot][s1,s2]
    __shared__ unsigned wmax[8][KSEG][8];
    const int t = threadIdx.x;
    const int g = blockIdx.x;
    const int iy = blockIdx.y;
    const int img = img0 + iy;
    const int wv = t >> 6;
    const int l = t & 63;
    const int k = g * 8 + wv;
    const int slot = l & 7;

    // issue global loads FIRST: latency hides under the LDS zeroing + barrier
    uint4 q0, q1, q2, q3;
    if (k <= 512) {   // wave-uniform
        const int kn = (1024 - k) & 1023;
        const uint4* ps = (const uint4*)(interm + ((size_t)iy * 1024 + k) * 512 + l * 8);
        const uint4* pn = (const uint4*)(interm + ((size_t)iy * 1024 + kn) * 512 + l * 8);
        q0 = ps[0]; q1 = ps[1];
        q2 = pn[0]; q3 = pn[1];
    }

    for (int i = t; i < 8 * 136; i += 512) {
        int w = i / 136;
        int rem = i - w * 136;
        int bb = rem >> 3, sl = rem & 7;
        wsum[w][bb][sl][0] = 0.f;
        wsum[w][bb][sl][1] = 0.f;
        wmax[w][bb][sl] = 0u;
    }
    __syncthreads();

    if (k <= 512) {   // wave-uniform
        // unpack (0.5 factors folded into c1/c2, r12)
        float2 a[16];
        {
            union QU { uint4 q; __half2 h[4]; } us, un;
#pragma unroll
            for (int c = 0; c < 2; ++c) {
                us.q = c ? q1 : q0;
                un.q = c ? q3 : q2;
#pragma unroll
                for (int j = 0; j < 4; ++j) {
                    int m = 4 * c + j;
                    float2 zs = __half22float2(us.h[j]);
                    float2 zn = __half22float2(un.h[j]);
                    a[BR4[m]]     = make_float2(zs.x + zn.x, zs.y - zn.y);
                    a[BR4[m + 8]] = make_float2(zs.y + zn.y, zn.x - zs.x);
                }
            }
        }

        fft16_regs(a);
        float2 u16;
        float angB = (float)l * (-6.28318530717958647692f / 1024.0f);
        twiddle_regs<false>(a, angB, &u16);
#if PERM32
        wave_fft_C_mix(a, l, u16);
#else
        wave_fft_C(a, l, u16);
#endif

        // ---- stats: two 8-row runs per lane (span <= 24 rows -> at most 2 bins) ----
        const int b = (int)(__brev((unsigned)l) >> 26);
#if PERM32
        const int bX = b ^ 1;
        const bool lohalf = (l < 32);
        const int offS = lohalf ? 0 : 8;
        const int hS0 = 16 * (lohalf ? b : bX) + offS;   // rows for slots 0..7
        const int hT0 = 16 * (lohalf ? bX : b) + offS;   // rows for slots 8..15
        const int hmin = 16 * (b & ~1) + offS;
        const int hmax = 16 * (b | 1) + offS + 7;
#else
        const int hS0 = 16 * b;
        const int hT0 = 16 * b + 8;
        const int hmin = 16 * b;
        const int hmax = 16 * b + 15;
#endif
        const float uf = (float)k * (1.0f / 1024.0f);
        const float uu = uf * uf;
        const float vbS = (float)(hS0 < 512 ? hS0 : hS0 - 1024);
        const float vbT = (float)(hT0 < 512 ? hT0 : hT0 - 1024);
        float vmn = (float)(hmin < 512 ? hmin : hmin - 1024) * (1.0f / 1024.0f);
        float vmx = (float)(hmax < 512 ? hmax : hmax - 1024) * (1.0f / 1024.0f);
        int binF = fast_bin(sqrtf(fmaf(vmn, vmn, uu)));
        int binL = fast_bin(sqrtf(fmaf(vmx, vmx, uu)));
        const int bHi = (binF > binL) ? binF : binL;
        const float Lmid = (0.707106781186547524f * (float)bHi) * 0.0625f;
        const float Lmid2 = Lmid * Lmid;

        // totals + B-side; A-side derived (sA = sT - sB)
        float sT1 = 0.f, sT2 = 0.f, mA = 0.f;
        float sB1 = 0.f, sB2 = 0.f, mB = 0.f;
#pragma unroll
        for (int r = 0; r < 16; ++r) {
            float vf = (r < 8 ? (vbS + (float)r) : (vbT + (float)(r - 8)))
                       * (1.0f / 1024.0f);
            float s = fmaf(vf, vf, uu);                    // exact rad^2
            float2 z = a[r];
            float p2 = fmaf(z.x, z.x, z.y * z.y);
            float m = sqrtf(p2);
            bool c = (s >= Lmid2);                         // row in bin bHi
            sT1 += m;
            sT2 += p2;
            mA = fmaxf(mA, c ? m : 0.f);
            sB1 += c ? 0.f : m;
            sB2 += c ? 0.f : p2;
            mB = fmaxf(mB, c ? 0.f : m);
        }
        // values are 2x reference: c1 = 1/2048, c2 = 1/4194304 (exact pow2, r12)
        const float c1 = 1.0f / 2048.0f;
        const float c2 = 1.0f / 4194304.0f;
        float sA1 = sT1 - sB1;
        float sA2 = sT2 - sB2;

        atomicAdd(&wsum[wv][bHi][slot][0], sA1 * c1);
        atomicAdd(&wsum[wv][bHi][slot][1], sA2 * c2);
        atomicMax(&wmax[wv][bHi][slot], __float_as_uint(mA * c1));
        if (bHi > 0) {
            atomicAdd(&wsum[wv][bHi - 1][slot][0], sB1 * c1);
            atomicAdd(&wsum[wv][bHi - 1][slot][1], sB2 * c2);
            atomicMax(&wmax[wv][bHi - 1][slot], __float_as_uint(mB * c1));
        }
    }
    __syncthreads();

    if (t < KSEG) {
        float aS = 0.f, bS = 0.f, cM = 0.f;
#pragma unroll
        for (int w = 0; w < 8; ++w)
#pragma unroll
            for (int sl = 0; sl < 8; ++sl) {
                aS += wsum[w][t][sl][0];
                bS += wsum[w][t][sl][1];
                cM = fmaxf(cM, __uint_as_float(wmax[w][t][sl]));
            }
        float* dstp = partials + ((size_t)img * NGRP + g) * (KSEG * 3) + t * 3;
        dstp[0] = aS; dstp[1] = bS; dstp[2] = cM;
    }
}

// ---------------- counts (exact reference binning, no int division) ------------------
__global__ __launch_bounds__(256) void k_counts(unsigned* __restrict__ counts) {
    int cnt[KSEG];
#pragma unroll
    for (int l = 0; l < KSEG; ++l) cnt[l] = 0;
    const int tid = blockIdx.x * 256 + threadIdx.x;
    const int stride = gridDim.x * 256;
    for (int i = tid; i < 1024 * 512; i += stride) {
        int h = i >> 9;
        int k = i & 511;
        int bin = radial_bin(h, k);
#pragma unroll
        for (int l = 0; l < KSEG; ++l) cnt[l] += (bin == l) ? 1 : 0;
    }
    for (int j = tid; j < 1024; j += stride) {   // k = 512 column
        int bin = radial_bin(j, 512);
#pragma unroll
        for (int l = 0; l < KSEG; ++l) cnt[l] += (bin == l) ? 1 : 0;
    }
    const int lane = threadIdx.x & 63;
#pragma unroll
    for (int l = 0; l < KSEG; ++l) {
        int c = cnt[l];
        for (int off = 32; off > 0; off >>= 1) c += __shfl_xor(c, off);
        if (lane == 0 && c > 0) atomicAdd(&counts[l], (unsigned)c);
    }
}

// ---------------- Kernel 3: finalize stats + MLP + LayerNorm -------------------------
__global__ __launch_bounds__(256) void k_mlp(const float* __restrict__ partials,
                                             const unsigned* __restrict__ counts,
                                             const float* __restrict__ W1,
                                             const float* __restrict__ b1,
                                             const float* __restrict__ W2,
                                             const float* __restrict__ b2,
                                             const float* __restrict__ gamma,
                                             const float* __restrict__ beta,
                                             float* __restrict__ out) {
    __shared__ float feat[FIN];
    __shared__ float h1s[FEAT];
    __shared__ float red[FEAT];
    const int b = blockIdx.x;
    const int t = threadIdx.x;
    if (t < 48) {
        int c = t / 16;
        int bin = t % 16;
        const float* p = partials + ((size_t)(b * 3 + c) * NGRP) * (KSEG * 3) + bin * 3;
        float s1 = 0.f, s2 = 0.f, mxv = 0.f;
        for (int gg = 0; gg < NGRP; ++gg) {
            s1 += p[gg * (KSEG * 3) + 0];
            s2 += p[gg * (KSEG * 3) + 1];
            mxv = fmaxf(mxv, p[gg * (KSEG * 3) + 2]);
        }
        float cntf = (float)counts[bin];
        float denom = cntf + 1e-8f;
        float mean = s1 / denom;
        float var = (s2 - 2.0f * mean * s1 + cntf * mean * mean) / denom;
        var = fmaxf(var, 0.0f);
        float sd = sqrtf(var);
        mxv = fmaxf(mxv, 0.0f);
        feat[bin * 9 + 0 + c] = mean;
        feat[bin * 9 + 3 + c] = mxv;
        feat[bin * 9 + 6 + c] = sd;
    }
    __syncthreads();

    float acc = b1[t];
    for (int i = 0; i < FIN; ++i) acc += feat[i] * W1[i * FEAT + t];
    acc = (acc >= 0.0f) ? acc : 0.2f * acc;
    h1s[t] = acc;
    __syncthreads();

    float acc2 = b2[t];
    for (int i = 0; i < FEAT; ++i) acc2 += h1s[i] * W2[i * FEAT + t];

    red[t] = acc2;
    __syncthreads();
    for (int off = 128; off > 0; off >>= 1) {
        if (t < off) red[t] += red[t + off];
        __syncthreads();
    }
    float mu = red[0] * (1.0f / 256.0f);
    __syncthreads();
    float dvt = acc2 - mu;
    red[t] = dvt * dvt;
    __syncthreads();
    for (int off = 128; off > 0; off >>= 1) {
        if (t < off) red[t] += red[t + off];
        __syncthreads();
    }
    float va = red[0] * (1.0f / 256.0f);
    out[(size_t)b * FEAT + t] = dvt / sqrtf(va + 1e-5f) * gamma[t] + beta[t];
}

// --------------------------------------------------------------------------------------
extern "C" void kernel_launch(void* const* d_in, const int* in_sizes, int n_in,
                              void* d_out, int out_size, void* d_ws, size_t ws_size,
                              hipStream_t stream) {
    const float* x     = (const float*)d_in[0];
    const float* W1    = (const float*)d_in[1];
    const float* b1    = (const float*)d_in[2];
    const float* W2    = (const float*)d_in[3];
    const float* b2    = (const float*)d_in[4];
    const float* gamma = (const float*)d_in[5];
    const float* beta  = (const float*)d_in[6];
    float* out = (float*)d_out;

    char* ws = (char*)d_ws;
    unsigned* counts = (unsigned*)ws;
    float* partials = (float*)(ws + 256);
    const size_t partialsBytes = (size_t)NIMG * NGRP * KSEG * 3 * sizeof(float);
    const size_t intermOff = (256 + partialsBytes + 255) & ~(size_t)255;
    __half2* interm = (__half2*)(ws + intermOff);
    const size_t perImg = (size_t)1024 * 512 * sizeof(__half2);

    long long avail = (long long)ws_size - (long long)intermOff;
    int chunk = (avail > 0) ? (int)(avail / (long long)perImg) : 0;
    if (chunk > CHUNK_IMGS) chunk = CHUNK_IMGS;   // L3-block the interm slab
    if (chunk < 1) chunk = 1;

    hipMemsetAsync(counts, 0, KSEG * sizeof(unsigned), stream);
    k_counts<<<dim3(128), dim3(256), 0, stream>>>(counts);

    for (int img0 = 0; img0 < NIMG; img0 += chunk) {
        int n = NIMG - img0;
        if (n > chunk) n = chunk;
        k_rowfft<<<dim3(32, n), dim3(1024), 0, stream>>>(x, interm, img0);
        k_colfft<<<dim3(NGRP, n), dim3(512), 0, stream>>>(interm, partials, img0);
    }

    k_mlp<<<dim3(32), dim3(256), 0, stream>>>(partials, counts, W1, b1, W2, b2,
                                              gamma, beta, out);
}

// Round 19
// 375.448 us; speedup vs baseline: 1.1414x; 1.0946x over previous
//
#include <hip/hip_runtime.h>
#include <hip/hip_fp16.h>
#include <math.h>

#define HH    1024
#define WWID  1024
#define WR    513
#define NIMG  96
#define NGRP  65
#define KSEG  17
#define FEAT  256
#define FIN   144

#if defined(__has_builtin)
#if __has_builtin(__builtin_amdgcn_permlane32_swap)
#define PERM32 1
#endif
#endif
#ifndef PERM32
#define PERM32 0
#endif

__device__ __forceinline__ float2 cmul(float2 a, float2 b) {
    return make_float2(a.x * b.x - a.y * b.y, a.x * b.y + a.y * b.x);
}

// exact reference binning (16 compares + sqrt) — used by k_counts
__device__ __forceinline__ int radial_bin(int hf, int k) {
    const float maxr = 0.707106781186547524f;
    float v = (float)(hf < 512 ? hf : hf - 1024) * (1.0f / 1024.0f);
    float u = (float)k * (1.0f / 1024.0f);
    float rad = sqrtf(u * u + v * v);
    int bin = 0;
#pragma unroll
    for (int l = 1; l <= 16; ++l) {
        float lower = (maxr * (float)l) * 0.0625f;
        bin += (rad >= lower) ? 1 : 0;
    }
    return bin;
}

// fast bin with exact boundary adjust (validated r6-r16)
__device__ __forceinline__ int fast_bin(float rad) {
    int c = (int)(rad * 22.62741699796952f);
    if (c > 16) c = 16;
    if (c < 16 && rad >= (0.707106781186547524f * (float)(c + 1)) * 0.0625f) c++;
    else if (rad < (0.707106781186547524f * (float)c) * 0.0625f) c--;
    return c;
}

__device__ constexpr int BR4[16] = {0,8,4,12,2,10,6,14,1,9,5,13,3,11,7,15};

// ---- cross-lane exchange: DPP where exact, ds ops otherwise (verified r12) ----------
template<int HALF>
__device__ __forceinline__ float sxl(float v, int addr32) {
    int vi = __float_as_int(v);
    if constexpr (HALF == 32)
        return __int_as_float(__builtin_amdgcn_ds_bpermute(addr32, vi));
    else if constexpr (HALF == 8)
        return __int_as_float(__builtin_amdgcn_update_dpp(vi, vi, 0x128, 0xF, 0xF, true));
    else if constexpr (HALF == 2)
        return __int_as_float(__builtin_amdgcn_update_dpp(vi, vi, 0x4E, 0xF, 0xF, true));
    else if constexpr (HALF == 1)
        return __int_as_float(__builtin_amdgcn_update_dpp(vi, vi, 0xB1, 0xF, 0xF, true));
    else
        return __int_as_float(__builtin_amdgcn_ds_swizzle(vi, (HALF << 10) | 0x1F));
}

template<int HALF>
__device__ __forceinline__ void fftC_stage(float2 a[16], int l, float2 u, int addr32) {
    const bool up = (l & HALF) != 0;
    const float sgn = up ? -1.0f : 1.0f;
    const float twx = up ? -u.x : 1.0f;   // down lanes: identity twiddle
    const float twy = up ? -u.y : 0.0f;
#pragma unroll
    for (int r = 0; r < 16; ++r) {
        float ox = sxl<HALF>(a[r].x, addr32);
        float oy = sxl<HALF>(a[r].y, addr32);
        float sx = fmaf(sgn, a[r].x, ox);   // down: a+o, up: o-a
        float sy = fmaf(sgn, a[r].y, oy);
        a[r].x = fmaf(sx, twx, -(sy * twy));
        a[r].y = fmaf(sx, twy, sy * twx);
    }
}

// stages 16..1 (shared). u must be W_32^l on entry.
__device__ __forceinline__ void wave_fft_C_tail(float2 a[16], int l, float2 u) {
    fftC_stage<16>(a, l, u, 0); u = cmul(u, u);
    fftC_stage<8>(a, l, u, 0);  u = cmul(u, u);
    fftC_stage<4>(a, l, u, 0);  u = cmul(u, u);
    fftC_stage<2>(a, l, u, 0);  u = cmul(u, u);
    fftC_stage<1>(a, l, u, 0);
}

// standard 64-pt DIF across lanes (rowfft). natural in -> bitrev out.
__device__ __forceinline__ void wave_fft_C(float2 a[16], int l, float2 u) {
    const int addr32 = ((l ^ 32) << 2);
    fftC_stage<32>(a, l, u, addr32);
    u = cmul(u, u);
    wave_fft_C_tail(a, l, u);
}

#if PERM32
// 64-pt DIF with stage-32 via permlane32_swap mixing (verified r11/r12).
__device__ __forceinline__ void wave_fft_C_mix(float2 a[16], int l, float2 u) {
    const bool lo = (l < 32);
    const float2 t = lo ? u : make_float2(-u.x, -u.y);
#pragma unroll
    for (int r = 0; r < 8; ++r) {
        unsigned ax = __float_as_uint(a[r].x), bx = __float_as_uint(a[r + 8].x);
        auto px = __builtin_amdgcn_permlane32_swap(ax, bx, false, false);
        unsigned ay = __float_as_uint(a[r].y), by = __float_as_uint(a[r + 8].y);
        auto py = __builtin_amdgcn_permlane32_swap(ay, by, false, false);
        float l0x = __uint_as_float(px[0]), h0x = __uint_as_float(px[1]);
        float l0y = __uint_as_float(py[0]), h0y = __uint_as_float(py[1]);
        a[r]     = make_float2(l0x + h0x, l0y + h0y);          // S_r
        a[r + 8] = cmul(make_float2(l0x - h0x, l0y - h0y), t); // T_r
    }
    u = cmul(u, u);
    wave_fft_C_tail(a, l, u);
}
#endif

// 16-pt DIT over registers: input reg r = element BR4[r] (bitrev order), natural out.
__device__ __forceinline__ void fft16_regs(float2 a[16]) {
    constexpr float TW16C[8] = {1.f, 0.9238795325112867f, 0.7071067811865476f,
                                0.3826834323650898f, 0.f, -0.3826834323650898f,
                                -0.7071067811865476f, -0.9238795325112867f};
    constexpr float TW16S[8] = {0.f, -0.3826834323650898f, -0.7071067811865476f,
                                -0.9238795325112867f, -1.f, -0.9238795325112867f,
                                -0.7071067811865476f, -0.3826834323650898f};
#pragma unroll
    for (int m = 2; m <= 16; m <<= 1) {
        const int half = m >> 1;
        const int tstep = 16 / m;
#pragma unroll
        for (int bse = 0; bse < 16; bse += m) {
#pragma unroll
            for (int jj = 0; jj < 8; ++jj) {
                if (jj < half) {
                    float2 w = make_float2(TW16C[jj * tstep], TW16S[jj * tstep]);
                    float2 tv = cmul(a[bse + half + jj], w);
                    float2 u0 = a[bse + jj];
                    a[bse + jj]        = make_float2(u0.x + tv.x, u0.y + tv.y);
                    a[bse + half + jj] = make_float2(u0.x - tv.x, u0.y - tv.y);
                }
            }
        }
    }
}

// twiddle a[r] *= wb^{e_r}; wb from __cosf/__sinf (|ang|<=0.39 rad), two-level chain.
template<bool PERM>  // e_r = PERM ? BR4[r] : r
__device__ __forceinline__ void twiddle_regs(float2 a[16], float ang, float2* w16out) {
    float2 w1 = make_float2(__cosf(ang), __sinf(ang));
    float2 w2 = cmul(w1, w1);
    float2 w3 = cmul(w2, w1);
    float2 w4 = cmul(w2, w2);
    float2 w8 = cmul(w4, w4);
    float2 w12 = cmul(w8, w4);
#pragma unroll
    for (int r = 1; r < 16; ++r) {
        const int e = PERM ? BR4[r] : r;
        float2 p = a[r];
        const int hi = e >> 2, lo = e & 3;
        if (hi == 1) p = cmul(p, w4);
        else if (hi == 2) p = cmul(p, w8);
        else if (hi == 3) p = cmul(p, w12);
        if (lo == 1) p = cmul(p, w1);
        else if (lo == 2) p = cmul(p, w2);
        else if (lo == 3) p = cmul(p, w3);
        a[r] = p;
    }
    if (w16out) *w16out = cmul(w8, w8);
}

// ---------------- Kernel 1: row FFTs (r16 config: 1024 thr, 32 blocks) ---------------
__global__ __launch_bounds__(1024) void k_rowfft(const float* __restrict__ x,
                                                 __half2* __restrict__ interm,
                                                 int img0) {
    __shared__ __half2 tile[1024][17];
    const int t = threadIdx.x;
    const int w = t >> 6;
    const int l = t & 63;
    const int blk = blockIdx.x;           // 0..31
    const int iy = blockIdx.y;
    const int img = img0 + iy;
    const int hA = ((w & 7) << 6) + 2 * blk + (w >> 3);
    const int hB = hA + 512;

    const float4* r1 = (const float4*)(x + ((size_t)img * HH + hA) * WWID) + 4 * l;
    const float4* r2 = (const float4*)(x + ((size_t)img * HH + hB) * WWID) + 4 * l;

    // consume each staged float4 immediately -> low staging pressure (r13 keep)
    float2 a[16];
#pragma unroll
    for (int c = 0; c < 4; ++c) {
        float4 v1 = r1[c];
        float4 v2 = r2[c];
        a[BR4[4 * c + 0]] = make_float2(v1.x, v2.x);
        a[BR4[4 * c + 1]] = make_float2(v1.y, v2.y);
        a[BR4[4 * c + 2]] = make_float2(v1.z, v2.z);
        a[BR4[4 * c + 3]] = make_float2(v1.w, v2.w);
    }

    float angL = (float)l * (-6.28318530717958647692f / 64.0f);
    wave_fft_C(a, l, make_float2(__cosf(angL), __sinf(angL)));

    const int b = (int)(__brev((unsigned)l) >> 26);
    float angB = (float)b * (-6.28318530717958647692f / 1024.0f);
    twiddle_regs<true>(a, angB, nullptr);
    fft16_regs(a);

#pragma unroll
    for (int r = 0; r < 16; ++r)
        tile[b + 64 * r][w] = __floats2half2_rn(a[r].x, a[r].y);
    __syncthreads();

    // vectorized write-out: 1024 rows x 4 uint4 = 4096 uint4 -> FOUR iterations
    uint4* gout4 = (uint4*)(interm + (size_t)iy * 1024 * 512);
#pragma unroll
    for (int it = 0; it < 4; ++it) {
        int idx = t + it * 1024;          // 0..4095
        int k = idx >> 2;                 // 0..1023
        int j = idx & 3;
        uint4 v;
        v.x = *(const unsigned*)&tile[k][4 * j + 0];
        v.y = *(const unsigned*)&tile[k][4 * j + 1];
        v.z = *(const unsigned*)&tile[k][4 * j + 2];
        v.w = *(const unsigned*)&tile[k][4 * j + 3];
        gout4[(size_t)k * 128 + blk * 4 + j] = v;
    }
}

// ------------- Kernel 2: column FFTs — loads hoisted above zero+barrier (r16) --------
__global__ __launch_bounds__(512) void k_colfft(const __half2* __restrict__ interm,
                                                float* __restrict__ partials,
                                                int img0) {
    __shared__ float wsum[8][KSEG][8][2];      // [wave][bin][slot][s1,s2]
    __shared__ unsigned wmax[8][KSEG][8];
    const int t = threadIdx.x;
    const int g = blockIdx.x;
    const int iy = blockIdx.y;
    const int img = img0 + iy;
    const int wv = t >> 6;
    const int l = t & 63;
    const int k = g * 8 + wv;
    const int slot = l & 7;

    // issue global loads FIRST: latency hides under the LDS zeroing + barrier
    uint4 q0, q1, q2, q3;
    if (k <= 512) {   // wave-uniform
        const int kn = (1024 - k) & 1023;
        const uint4* ps = (const uint4*)(interm + ((size_t)iy * 1024 + k) * 512 + l * 8);
        const uint4* pn = (const uint4*)(interm + ((size_t)iy * 1024 + kn) * 512 + l * 8);
        q0 = ps[0]; q1 = ps[1];
        q2 = pn[0]; q3 = pn[1];
    }

    for (int i = t; i < 8 * 136; i += 512) {
        int w = i / 136;
        int rem = i - w * 136;
        int bb = rem >> 3, sl = rem & 7;
        wsum[w][bb][sl][0] = 0.f;
        wsum[w][bb][sl][1] = 0.f;
        wmax[w][bb][sl] = 0u;
    }
    __syncthreads();

    if (k <= 512) {   // wave-uniform
        // unpack (0.5 factors folded into c1/c2, r12)
        float2 a[16];
        {
            union QU { uint4 q; __half2 h[4]; } us, un;
#pragma unroll
            for (int c = 0; c < 2; ++c) {
                us.q = c ? q1 : q0;
                un.q = c ? q3 : q2;
#pragma unroll
                for (int j = 0; j < 4; ++j) {
                    int m = 4 * c + j;
                    float2 zs = __half22float2(us.h[j]);
                    float2 zn = __half22float2(un.h[j]);
                    a[BR4[m]]     = make_float2(zs.x + zn.x, zs.y - zn.y);
                    a[BR4[m + 8]] = make_float2(zs.y + zn.y, zn.x - zs.x);
                }
            }
        }

        fft16_regs(a);
        float2 u16;
        float angB = (float)l * (-6.28318530717958647692f / 1024.0f);
        twiddle_regs<false>(a, angB, &u16);
#if PERM32
        wave_fft_C_mix(a, l, u16);
#else
        wave_fft_C(a, l, u16);
#endif

        // ---- stats: two 8-row runs per lane (span <= 24 rows -> at most 2 bins) ----
        const int b = (int)(__brev((unsigned)l) >> 26);
#if PERM32
        const int bX = b ^ 1;
        const bool lohalf = (l < 32);
        const int offS = lohalf ? 0 : 8;
        const int hS0 = 16 * (lohalf ? b : bX) + offS;   // rows for slots 0..7
        const int hT0 = 16 * (lohalf ? bX : b) + offS;   // rows for slots 8..15
        const int hmin = 16 * (b & ~1) + offS;
        const int hmax = 16 * (b | 1) + offS + 7;
#else
        const int hS0 = 16 * b;
        const int hT0 = 16 * b + 8;
        const int hmin = 16 * b;
        const int hmax = 16 * b + 15;
#endif
        const float uf = (float)k * (1.0f / 1024.0f);
        const float uu = uf * uf;
        const float vbS = (float)(hS0 < 512 ? hS0 : hS0 - 1024);
        const float vbT = (float)(hT0 < 512 ? hT0 : hT0 - 1024);
        float vmn = (float)(hmin < 512 ? hmin : hmin - 1024) * (1.0f / 1024.0f);
        float vmx = (float)(hmax < 512 ? hmax : hmax - 1024) * (1.0f / 1024.0f);
        int binF = fast_bin(sqrtf(fmaf(vmn, vmn, uu)));
        int binL = fast_bin(sqrtf(fmaf(vmx, vmx, uu)));
        const int bHi = (binF > binL) ? binF : binL;
        const float Lmid = (0.707106781186547524f * (float)bHi) * 0.0625f;
        const float Lmid2 = Lmid * Lmid;

        // totals + B-side; A-side derived (sA = sT - sB)
        float sT1 = 0.f, sT2 = 0.f, mA = 0.f;
        float sB1 = 0.f, sB2 = 0.f, mB = 0.f;
#pragma unroll
        for (int r = 0; r < 16; ++r) {
            float vf = (r < 8 ? (vbS + (float)r) : (vbT + (float)(r - 8)))
                       * (1.0f / 1024.0f);
            float s = fmaf(vf, vf, uu);                    // exact rad^2
            float2 z = a[r];
            float p2 = fmaf(z.x, z.x, z.y * z.y);
            float m = sqrtf(p2);
            bool c = (s >= Lmid2);                         // row in bin bHi
            sT1 += m;
            sT2 += p2;
            mA = fmaxf(mA, c ? m : 0.f);
            sB1 += c ? 0.f : m;
            sB2 += c ? 0.f : p2;
            mB = fmaxf(mB, c ? 0.f : m);
        }
        // values are 2x reference: c1 = 1/2048, c2 = 1/4194304 (exact pow2, r12)
        const float c1 = 1.0f / 2048.0f;
        const float c2 = 1.0f / 4194304.0f;
        float sA1 = sT1 - sB1;
        float sA2 = sT2 - sB2;

        atomicAdd(&wsum[wv][bHi][slot][0], sA1 * c1);
        atomicAdd(&wsum[wv][bHi][slot][1], sA2 * c2);
        atomicMax(&wmax[wv][bHi][slot], __float_as_uint(mA * c1));
        if (bHi > 0) {
            atomicAdd(&wsum[wv][bHi - 1][slot][0], sB1 * c1);
            atomicAdd(&wsum[wv][bHi - 1][slot][1], sB2 * c2);
            atomicMax(&wmax[wv][bHi - 1][slot], __float_as_uint(mB * c1));
        }
    }
    __syncthreads();

    if (t < KSEG) {
        float aS = 0.f, bS = 0.f, cM = 0.f;
#pragma unroll
        for (int w = 0; w < 8; ++w)
#pragma unroll
            for (int sl = 0; sl < 8; ++sl) {
                aS += wsum[w][t][sl][0];
                bS += wsum[w][t][sl][1];
                cM = fmaxf(cM, __uint_as_float(wmax[w][t][sl]));
            }
        float* dstp = partials + ((size_t)img * NGRP + g) * (KSEG * 3) + t * 3;
        dstp[0] = aS; dstp[1] = bS; dstp[2] = cM;
    }
}

// ---------------- counts (exact reference binning, no int division) ------------------
__global__ __launch_bounds__(256) void k_counts(unsigned* __restrict__ counts) {
    int cnt[KSEG];
#pragma unroll
    for (int l = 0; l < KSEG; ++l) cnt[l] = 0;
    const int tid = blockIdx.x * 256 + threadIdx.x;
    const int stride = gridDim.x * 256;
    for (int i = tid; i < 1024 * 512; i += stride) {
        int h = i >> 9;
        int k = i & 511;
        int bin = radial_bin(h, k);
#pragma unroll
        for (int l = 0; l < KSEG; ++l) cnt[l] += (bin == l) ? 1 : 0;
    }
    for (int j = tid; j < 1024; j += stride) {   // k = 512 column
        int bin = radial_bin(j, 512);
#pragma unroll
        for (int l = 0; l < KSEG; ++l) cnt[l] += (bin == l) ? 1 : 0;
    }
    const int lane = threadIdx.x & 63;
#pragma unroll
    for (int l = 0; l < KSEG; ++l) {
        int c = cnt[l];
        for (int off = 32; off > 0; off >>= 1) c += __shfl_xor(c, off);
        if (lane == 0 && c > 0) atomicAdd(&counts[l], (unsigned)c);
    }
}

// ---------------- Kernel 3: finalize stats + MLP + LayerNorm -------------------------
__global__ __launch_bounds__(256) void k_mlp(const float* __restrict__ partials,
                                             const unsigned* __restrict__ counts,
                                             const float* __restrict__ W1,
                                             const float* __restrict__ b1,
                                             const float* __restrict__ W2,
                                             const float* __restrict__ b2,
                                             const float* __restrict__ gamma,
                                             const float* __restrict__ beta,
                                             float* __restrict__ out) {
    __shared__ float feat[FIN];
    __shared__ float h1s[FEAT];
    __shared__ float red[FEAT];
    const int b = blockIdx.x;
    const int t = threadIdx.x;
    if (t < 48) {
        int c = t / 16;
        int bin = t % 16;
        const float* p = partials + ((size_t)(b * 3 + c) * NGRP) * (KSEG * 3) + bin * 3;
        float s1 = 0.f, s2 = 0.f, mxv = 0.f;
        for (int gg = 0; gg < NGRP; ++gg) {
            s1 += p[gg * (KSEG * 3) + 0];
            s2 += p[gg * (KSEG * 3) + 1];
            mxv = fmaxf(mxv, p[gg * (KSEG * 3) + 2]);
        }
        float cntf = (float)counts[bin];
        float denom = cntf + 1e-8f;
        float mean = s1 / denom;
        float var = (s2 - 2.0f * mean * s1 + cntf * mean * mean) / denom;
        var = fmaxf(var, 0.0f);
        float sd = sqrtf(var);
        mxv = fmaxf(mxv, 0.0f);
        feat[bin * 9 + 0 + c] = mean;
        feat[bin * 9 + 3 + c] = mxv;
        feat[bin * 9 + 6 + c] = sd;
    }
    __syncthreads();

    float acc = b1[t];
    for (int i = 0; i < FIN; ++i) acc += feat[i] * W1[i * FEAT + t];
    acc = (acc >= 0.0f) ? acc : 0.2f * acc;
    h1s[t] = acc;
    __syncthreads();

    float acc2 = b2[t];
    for (int i = 0; i < FEAT; ++i) acc2 += h1s[i] * W2[i * FEAT + t];

    red[t] = acc2;
    __syncthreads();
    for (int off = 128; off > 0; off >>= 1) {
        if (t < off) red[t] += red[t + off];
        __syncthreads();
    }
    float mu = red[0] * (1.0f / 256.0f);
    __syncthreads();
    float dvt = acc2 - mu;
    red[t] = dvt * dvt;
    __syncthreads();
    for (int off = 128; off > 0; off >>= 1) {
        if (t < off) red[t] += red[t + off];
        __syncthreads();
    }
    float va = red[0] * (1.0f / 256.0f);
    out[(size_t)b * FEAT + t] = dvt / sqrtf(va + 1e-5f) * gamma[t] + beta[t];
}

// --------------------------------------------------------------------------------------
extern "C" void kernel_launch(void* const* d_in, const int* in_sizes, int n_in,
                              void* d_out, int out_size, void* d_ws, size_t ws_size,
                              hipStream_t stream) {
    const float* x     = (const float*)d_in[0];
    const float* W1    = (const float*)d_in[1];
    const float* b1    = (const float*)d_in[2];
    const float* W2    = (const float*)d_in[3];
    const float* b2    = (const float*)d_in[4];
    const float* gamma = (const float*)d_in[5];
    const float* beta  = (const float*)d_in[6];
    float* out = (float*)d_out;

    char* ws = (char*)d_ws;
    unsigned* counts = (unsigned*)ws;
    float* partials = (float*)(ws + 256);
    const size_t partialsBytes = (size_t)NIMG * NGRP * KSEG * 3 * sizeof(float);
    const size_t intermOff = (256 + partialsBytes + 255) & ~(size_t)255;
    __half2* interm = (__half2*)(ws + intermOff);
    const size_t perImg = (size_t)1024 * 512 * sizeof(__half2);

    long long avail = (long long)ws_size - (long long)intermOff;
    int chunk = (avail > 0) ? (int)(avail / (long long)perImg) : 0;
    if (chunk > NIMG) chunk = NIMG;
    if (chunk < 1) chunk = 1;

    hipMemsetAsync(counts, 0, KSEG * sizeof(unsigned), stream);
    k_counts<<<dim3(128), dim3(256), 0, stream>>>(counts);

    for (int img0 = 0; img0 < NIMG; img0 += chunk) {
        int n = NIMG - img0;
        if (n > chunk) n = chunk;
        k_rowfft<<<dim3(32, n), dim3(1024), 0, stream>>>(x, interm, img0);
        k_colfft<<<dim3(NGRP, n), dim3(512), 0, stream>>>(interm, partials, img0);
    }

    k_mlp<<<dim3(32), dim3(256), 0, stream>>>(partials, counts, W1, b1, W2, b2,
                                              gamma, beta, out);
}